// Round 1
// baseline (1547.543 us; speedup 1.0000x reference)
//
#include <hip/hip_runtime.h>
#include <math.h>

#define COLS 4096
#define COLS4 (COLS / 4)

// ---------------------------------------------------------------------------
// Stage 1: per-chunk column min/max partials.
// grid.x covers columns (4 float4-cols per thread-block-row: 256 thr * 4 cols),
// grid.y = chunk index. Each thread owns 4 consecutive columns via float4.
// Wave access: 64 lanes * 16B = 1KB contiguous -> fully coalesced.
// ---------------------------------------------------------------------------
__global__ __launch_bounds__(256) void col_minmax_stage1(
    const float* __restrict__ src, int rows, int rows_per_chunk,
    float* __restrict__ ws_min, float* __restrict__ ws_max)
{
    int c4 = blockIdx.x * blockDim.x + threadIdx.x;  // float4 column index
    if (c4 >= COLS4) return;
    int r0 = blockIdx.y * rows_per_chunk;
    int r1 = r0 + rows_per_chunk;
    if (r1 > rows) r1 = rows;

    float4 vmin = make_float4( INFINITY,  INFINITY,  INFINITY,  INFINITY);
    float4 vmax = make_float4(-INFINITY, -INFINITY, -INFINITY, -INFINITY);
    const float4* s4 = (const float4*)src;
    for (int r = r0; r < r1; ++r) {
        float4 v = s4[(size_t)r * COLS4 + c4];
        vmin.x = fminf(vmin.x, v.x); vmax.x = fmaxf(vmax.x, v.x);
        vmin.y = fminf(vmin.y, v.y); vmax.y = fmaxf(vmax.y, v.y);
        vmin.z = fminf(vmin.z, v.z); vmax.z = fmaxf(vmax.z, v.z);
        vmin.w = fminf(vmin.w, v.w); vmax.w = fmaxf(vmax.w, v.w);
    }
    size_t o = (size_t)blockIdx.y * COLS4 + c4;
    ((float4*)ws_min)[o] = vmin;
    ((float4*)ws_max)[o] = vmax;
}

// ---------------------------------------------------------------------------
// Stage 2: reduce chunk partials -> final per-column min/max.
// ---------------------------------------------------------------------------
__global__ __launch_bounds__(256) void col_minmax_stage2(
    const float* __restrict__ ws_min, const float* __restrict__ ws_max,
    int chunks, float* __restrict__ out_min, float* __restrict__ out_max)
{
    int c = blockIdx.x * blockDim.x + threadIdx.x;
    if (c >= COLS) return;
    float mn = INFINITY, mx = -INFINITY;
    for (int k = 0; k < chunks; ++k) {
        mn = fminf(mn, ws_min[(size_t)k * COLS + c]);
        mx = fmaxf(mx, ws_max[(size_t)k * COLS + c]);
    }
    out_min[c] = mn;
    out_max[c] = mx;
}

// ---------------------------------------------------------------------------
// Row min/max + FIRST-OCCURRENCE argmin/argmax. One 256-thread block per row.
// Per-thread: strict compare while iterating ascending indices -> keeps first
// occurrence. Cross-thread: lexicographic (value, index) LDS tree reduction.
// Indices stored as float32 (harness reads d_out as fp32; idx<=4095 exact).
// ---------------------------------------------------------------------------
__global__ __launch_bounds__(256) void row_minmax_arg(
    const float* __restrict__ w,
    float* __restrict__ out_min, float* __restrict__ out_max,
    float* __restrict__ out_imin, float* __restrict__ out_imax)
{
    __shared__ float s_mn[256], s_mx[256];
    __shared__ int   s_in[256], s_ix[256];

    int row = blockIdx.x;
    const float4* w4 = (const float4*)(w + (size_t)row * COLS);

    float mn = INFINITY, mx = -INFINITY;
    int imn = 0, imx = 0;
    for (int i = threadIdx.x; i < COLS4; i += 256) {
        float4 v = w4[i];
        int b = i << 2;
        if (v.x < mn) { mn = v.x; imn = b;     }
        if (v.x > mx) { mx = v.x; imx = b;     }
        if (v.y < mn) { mn = v.y; imn = b + 1; }
        if (v.y > mx) { mx = v.y; imx = b + 1; }
        if (v.z < mn) { mn = v.z; imn = b + 2; }
        if (v.z > mx) { mx = v.z; imx = b + 2; }
        if (v.w < mn) { mn = v.w; imn = b + 3; }
        if (v.w > mx) { mx = v.w; imx = b + 3; }
    }

    int t = threadIdx.x;
    s_mn[t] = mn; s_in[t] = imn;
    s_mx[t] = mx; s_ix[t] = imx;
    __syncthreads();

    for (int s = 128; s > 0; s >>= 1) {
        if (t < s) {
            float ov = s_mn[t + s]; int oi = s_in[t + s];
            if (ov < s_mn[t] || (ov == s_mn[t] && oi < s_in[t])) { s_mn[t] = ov; s_in[t] = oi; }
            ov = s_mx[t + s]; oi = s_ix[t + s];
            if (ov > s_mx[t] || (ov == s_mx[t] && oi < s_ix[t])) { s_mx[t] = ov; s_ix[t] = oi; }
        }
        __syncthreads();
    }

    if (t == 0) {
        out_min[row]  = s_mn[0];
        out_max[row]  = s_mx[0];
        out_imin[row] = (float)s_in[0];
        out_imax[row] = (float)s_ix[0];
    }
}

extern "C" void kernel_launch(void* const* d_in, const int* in_sizes, int n_in,
                              void* d_out, int out_size, void* d_ws, size_t ws_size,
                              hipStream_t stream) {
    const float* x = (const float*)d_in[0];
    const float* w = (const float*)d_in[1];
    float* out = (float*)d_out;

    int rows_x = in_sizes[0] / COLS;  // 65536
    int rows_w = in_sizes[1] / COLS;  // 4096

    // Pick chunk counts; shrink if workspace is small (defensive).
    int chunks_x = 128, chunks_w = 32;
    size_t per = (size_t)COLS * 2 * sizeof(float);
    while ((size_t)(chunks_x + chunks_w) * per > ws_size && chunks_x > 4) {
        chunks_x >>= 1;
        if (chunks_w > 4) chunks_w >>= 1;
    }
    int rpc_x = (rows_x + chunks_x - 1) / chunks_x;
    int rpc_w = (rows_w + chunks_w - 1) / chunks_w;

    float* ws_min_x = (float*)d_ws;
    float* ws_max_x = ws_min_x + (size_t)chunks_x * COLS;
    float* ws_min_w = ws_max_x + (size_t)chunks_x * COLS;
    float* ws_max_w = ws_min_w + (size_t)chunks_w * COLS;

    float* x_min     = out + 0 * COLS;
    float* x_max     = out + 1 * COLS;
    float* w_col_min = out + 2 * COLS;
    float* w_col_max = out + 3 * COLS;
    float* w_row_min = out + 4 * COLS;
    float* w_row_max = out + 5 * COLS;
    float* w_imin    = out + 6 * COLS;
    float* w_imax    = out + 7 * COLS;

    dim3 blk(256);
    // x column stats (the 1.07 GB read — dominates)
    col_minmax_stage1<<<dim3(COLS4 / 256, chunks_x), blk, 0, stream>>>(
        x, rows_x, rpc_x, ws_min_x, ws_max_x);
    // w column stats
    col_minmax_stage1<<<dim3(COLS4 / 256, chunks_w), blk, 0, stream>>>(
        w, rows_w, rpc_w, ws_min_w, ws_max_w);
    // w row stats + argmin/argmax
    row_minmax_arg<<<dim3(rows_w), blk, 0, stream>>>(
        w, w_row_min, w_row_max, w_imin, w_imax);
    // finals
    col_minmax_stage2<<<dim3(COLS / 256), blk, 0, stream>>>(
        ws_min_x, ws_max_x, chunks_x, x_min, x_max);
    col_minmax_stage2<<<dim3(COLS / 256), blk, 0, stream>>>(
        ws_min_w, ws_max_w, chunks_w, w_col_min, w_col_max);
}

// Round 2
// 1418.062 us; speedup vs baseline: 1.0913x; 1.0913x over previous
//
#include <hip/hip_runtime.h>
#include <math.h>

#define COLS 4096
#define COLS4 1024  // COLS / 4

// ---------------------------------------------------------------------------
// Stage 1: per-chunk column min/max partials — sequential-streaming version.
// One block per row-chunk. Each block covers the FULL 16 KB row each
// iteration: thread t owns float4-columns {t, t+256, t+512, t+768}, so the
// block's 256 threads * 4 j-slots * 16 B = 16 KB = one whole row, and rows
// are walked sequentially -> each block streams one contiguous memory region
// front-to-back (same pattern as the 6.4 TB/s fill kernel). 4 independent
// 16 B loads per thread per row give ample MLP; 8 float4 accumulators
// (32 VGPRs) keep occupancy high.
// ---------------------------------------------------------------------------
__global__ __launch_bounds__(256) void col_minmax_stage1(
    const float* __restrict__ src, int rows, int rows_per_chunk,
    float* __restrict__ ws_min, float* __restrict__ ws_max)
{
    int chunk = blockIdx.x;
    int r0 = chunk * rows_per_chunk;
    int r1 = r0 + rows_per_chunk;
    if (r1 > rows) r1 = rows;

    float4 mn[4], mx[4];
#pragma unroll
    for (int j = 0; j < 4; ++j) {
        mn[j] = make_float4( INFINITY,  INFINITY,  INFINITY,  INFINITY);
        mx[j] = make_float4(-INFINITY, -INFINITY, -INFINITY, -INFINITY);
    }

    const float4* p = (const float4*)src + (size_t)r0 * COLS4 + threadIdx.x;
    for (int r = r0; r < r1; ++r, p += COLS4) {
#pragma unroll
        for (int j = 0; j < 4; ++j) {
            float4 v = p[j * 256];
            mn[j].x = fminf(mn[j].x, v.x); mx[j].x = fmaxf(mx[j].x, v.x);
            mn[j].y = fminf(mn[j].y, v.y); mx[j].y = fmaxf(mx[j].y, v.y);
            mn[j].z = fminf(mn[j].z, v.z); mx[j].z = fmaxf(mx[j].z, v.z);
            mn[j].w = fminf(mn[j].w, v.w); mx[j].w = fmaxf(mx[j].w, v.w);
        }
    }

    float4* omn = (float4*)ws_min + (size_t)chunk * COLS4 + threadIdx.x;
    float4* omx = (float4*)ws_max + (size_t)chunk * COLS4 + threadIdx.x;
#pragma unroll
    for (int j = 0; j < 4; ++j) {
        omn[j * 256] = mn[j];
        omx[j * 256] = mx[j];
    }
}

// ---------------------------------------------------------------------------
// Chunk-partial reducer: layout [chunk][COLS]. grid.y = output groups, each
// reducing cpg input chunks; grid.x*256 threads cover COLS4 float4-columns.
// Consecutive threads read consecutive float4 -> coalesced.
// ---------------------------------------------------------------------------
__global__ __launch_bounds__(256) void col_minmax_reduce(
    const float* __restrict__ in_min, const float* __restrict__ in_max,
    int n_in, int cpg,
    float* __restrict__ out_min, float* __restrict__ out_max)
{
    int c4 = blockIdx.x * 256 + threadIdx.x;
    if (c4 >= COLS4) return;
    int g = blockIdx.y;
    int k0 = g * cpg;
    int k1 = k0 + cpg;
    if (k1 > n_in) k1 = n_in;

    float4 mn = make_float4( INFINITY,  INFINITY,  INFINITY,  INFINITY);
    float4 mx = make_float4(-INFINITY, -INFINITY, -INFINITY, -INFINITY);
    for (int k = k0; k < k1; ++k) {
        float4 a = ((const float4*)in_min)[(size_t)k * COLS4 + c4];
        float4 b = ((const float4*)in_max)[(size_t)k * COLS4 + c4];
        mn.x = fminf(mn.x, a.x); mx.x = fmaxf(mx.x, b.x);
        mn.y = fminf(mn.y, a.y); mx.y = fmaxf(mx.y, b.y);
        mn.z = fminf(mn.z, a.z); mx.z = fmaxf(mx.z, b.z);
        mn.w = fminf(mn.w, a.w); mx.w = fmaxf(mx.w, b.w);
    }
    ((float4*)out_min)[(size_t)g * COLS4 + c4] = mn;
    ((float4*)out_max)[(size_t)g * COLS4 + c4] = mx;
}

// ---------------------------------------------------------------------------
// Row min/max + FIRST-OCCURRENCE argmin/argmax. One 256-thread block per row.
// Per-thread strict compare over ascending indices keeps first occurrence;
// cross-thread lexicographic (value, index) LDS tree reduction.
// Indices stored as float32 (idx <= 4095, exact in fp32).
// ---------------------------------------------------------------------------
__global__ __launch_bounds__(256) void row_minmax_arg(
    const float* __restrict__ w,
    float* __restrict__ out_min, float* __restrict__ out_max,
    float* __restrict__ out_imin, float* __restrict__ out_imax)
{
    __shared__ float s_mn[256], s_mx[256];
    __shared__ int   s_in[256], s_ix[256];

    int row = blockIdx.x;
    const float4* w4 = (const float4*)(w + (size_t)row * COLS);

    float mn = INFINITY, mx = -INFINITY;
    int imn = 0, imx = 0;
#pragma unroll
    for (int u = 0; u < COLS4 / 256; ++u) {
        int i = u * 256 + threadIdx.x;
        float4 v = w4[i];
        int b = i << 2;
        if (v.x < mn) { mn = v.x; imn = b;     }
        if (v.x > mx) { mx = v.x; imx = b;     }
        if (v.y < mn) { mn = v.y; imn = b + 1; }
        if (v.y > mx) { mx = v.y; imx = b + 1; }
        if (v.z < mn) { mn = v.z; imn = b + 2; }
        if (v.z > mx) { mx = v.z; imx = b + 2; }
        if (v.w < mn) { mn = v.w; imn = b + 3; }
        if (v.w > mx) { mx = v.w; imx = b + 3; }
    }

    int t = threadIdx.x;
    s_mn[t] = mn; s_in[t] = imn;
    s_mx[t] = mx; s_ix[t] = imx;
    __syncthreads();

    for (int s = 128; s > 0; s >>= 1) {
        if (t < s) {
            float ov = s_mn[t + s]; int oi = s_in[t + s];
            if (ov < s_mn[t] || (ov == s_mn[t] && oi < s_in[t])) { s_mn[t] = ov; s_in[t] = oi; }
            ov = s_mx[t + s]; oi = s_ix[t + s];
            if (ov > s_mx[t] || (ov == s_mx[t] && oi < s_ix[t])) { s_mx[t] = ov; s_ix[t] = oi; }
        }
        __syncthreads();
    }

    if (t == 0) {
        out_min[row]  = s_mn[0];
        out_max[row]  = s_mx[0];
        out_imin[row] = (float)s_in[0];
        out_imax[row] = (float)s_ix[0];
    }
}

extern "C" void kernel_launch(void* const* d_in, const int* in_sizes, int n_in,
                              void* d_out, int out_size, void* d_ws, size_t ws_size,
                              hipStream_t stream) {
    const float* x = (const float*)d_in[0];
    const float* w = (const float*)d_in[1];
    float* out = (float*)d_out;

    int rows_x = in_sizes[0] / COLS;  // 65536
    int rows_w = in_sizes[1] / COLS;  // 4096

    // x: 1024 chunks of 64 rows -> 4096 waves (16/CU) in stage 1.
    const int chunks_x = 1024, g2_x = 32;
    // w: 256 chunks of 16 rows.
    const int chunks_w = 256, g2_w = 8;
    int rpc_x = (rows_x + chunks_x - 1) / chunks_x;
    int rpc_w = (rows_w + chunks_w - 1) / chunks_w;

    // Workspace layout (ws is >= 4 GB; we use < 50 MB).
    float* ws_min_x  = (float*)d_ws;
    float* ws_max_x  = ws_min_x  + (size_t)chunks_x * COLS;
    float* ws2_min_x = ws_max_x  + (size_t)chunks_x * COLS;
    float* ws2_max_x = ws2_min_x + (size_t)g2_x * COLS;
    float* ws_min_w  = ws2_max_x + (size_t)g2_x * COLS;
    float* ws_max_w  = ws_min_w  + (size_t)chunks_w * COLS;
    float* ws2_min_w = ws_max_w  + (size_t)chunks_w * COLS;
    float* ws2_max_w = ws2_min_w + (size_t)g2_w * COLS;

    float* x_min     = out + 0 * COLS;
    float* x_max     = out + 1 * COLS;
    float* w_col_min = out + 2 * COLS;
    float* w_col_max = out + 3 * COLS;
    float* w_row_min = out + 4 * COLS;
    float* w_row_max = out + 5 * COLS;
    float* w_imin    = out + 6 * COLS;
    float* w_imax    = out + 7 * COLS;

    dim3 blk(256);

    // x column stats (the 1.07 GB stream — dominates)
    col_minmax_stage1<<<dim3(chunks_x), blk, 0, stream>>>(
        x, rows_x, rpc_x, ws_min_x, ws_max_x);
    // w column stats
    col_minmax_stage1<<<dim3(chunks_w), blk, 0, stream>>>(
        w, rows_w, rpc_w, ws_min_w, ws_max_w);
    // w row stats + argmin/argmax
    row_minmax_arg<<<dim3(rows_w), blk, 0, stream>>>(
        w, w_row_min, w_row_max, w_imin, w_imax);

    // x partial reduce: 1024 -> 32 -> 1
    col_minmax_reduce<<<dim3(COLS4 / 256, g2_x), blk, 0, stream>>>(
        ws_min_x, ws_max_x, chunks_x, chunks_x / g2_x, ws2_min_x, ws2_max_x);
    col_minmax_reduce<<<dim3(COLS4 / 256, 1), blk, 0, stream>>>(
        ws2_min_x, ws2_max_x, g2_x, g2_x, x_min, x_max);

    // w partial reduce: 256 -> 8 -> 1
    col_minmax_reduce<<<dim3(COLS4 / 256, g2_w), blk, 0, stream>>>(
        ws_min_w, ws_max_w, chunks_w, chunks_w / g2_w, ws2_min_w, ws2_max_w);
    col_minmax_reduce<<<dim3(COLS4 / 256, 1), blk, 0, stream>>>(
        ws2_min_w, ws2_max_w, g2_w, g2_w, w_col_min, w_col_max);
}